// Round 2
// 258.227 us; speedup vs baseline: 1.1589x; 1.1589x over previous
//
#include <hip/hip_runtime.h>
#include <stdint.h>

#define C_ITEMS 16384
#define NCLS 16
#define HSTRIDE 16386   // AP hist entries per class (opt in [1, P+1])

// ---- workspace layout (bytes) ----
static const size_t OFF_COL  = 0;                                     // 16*16384 f32 col-major scores
static const size_t OFF_SPOS = 1u << 20;                              // sorted positives (desc) per class
static const size_t OFF_SNEG = 2u << 20;                              // per-(class,rank) negative score (f32)
static const size_t OFF_PACK = 3u << 20;                              // bucket-scattered (low16key,idx)
static const size_t OFF_HIST = 4u << 20;                              // 16 * HSTRIDE u32 (AP hist)
static const size_t OFF_CNT  = OFF_HIST + (size_t)NCLS * HSTRIDE * 4; // 16 u32 P-counts
static const size_t OFF_ACCS = OFF_CNT + 64;                          // 16 double
static const size_t OFF_ACCV = OFF_ACCS + 128;                        // 16 double
static const size_t OFF_TOT  = OFF_ACCV + 128;                        // 1 double
static const size_t OFF_PC   = OFF_TOT + 8;                           // 16 u32 positive-collect counters
static const size_t OFF_H1   = (OFF_PC + 64 + 255) & ~(size_t)255;    // 16 * 65536 u32 bucket hist
static const size_t OFF_PPK  = OFF_H1 + (((size_t)NCLS << 16) * 4);   // 16 * 16384 u64 positive keys
static const size_t ZERO_BYTES = OFF_PPK - OFF_HIST;                  // zero hist..h1 end
// aopt (anchor opts, 16 * 512 u32) reuses the ppk region: written by k_anchor
// strictly after k_posrank2 consumed ppk. No extra workspace, no zeroing needed.

__device__ __forceinline__ unsigned ordkey(float f) {
  unsigned b = __float_as_uint(f);
  return (b & 0x80000000u) ? ~b : (b | 0x80000000u);   // monotone float->uint
}

__global__ void k_zero(unsigned* p, int n) {
  int stride = gridDim.x * blockDim.x;
  for (int t = blockIdx.x * blockDim.x + threadIdx.x; t < n; t += stride) p[t] = 0u;
}

// transpose + per-class negative bucket histogram (65536 buckets on ordkey>>16)
__global__ void k_prep(const float* __restrict__ scores, const int* __restrict__ labels,
                       float* __restrict__ col, unsigned* __restrict__ h1) {
  int t = blockIdx.x * 256 + threadIdx.x;      // 0..262143
  float v = scores[t];
  int i = t >> 4, c = t & 15;
  col[(c << 14) | i] = v;
  if (labels[i] != c)
    atomicAdd(&h1[(c << 16) + (ordkey(v) >> 16)], 1u);
}

__global__ void k_counts(const int* __restrict__ labels, unsigned* __restrict__ counts) {
  __shared__ unsigned lc[NCLS];
  int tid = threadIdx.x;
  if (tid < NCLS) lc[tid] = 0;
  __syncthreads();
  int m = blockIdx.x * 256 + tid;
  atomicAdd(&lc[labels[m] & 15], 1u);
  __syncthreads();
  if (tid < NCLS && lc[tid]) atomicAdd(&counts[tid], lc[tid]);
}

// ---- positives: collect (key,idx) per class into global lists ----
__global__ void k_poscollect(const float* __restrict__ scores, const int* __restrict__ labels,
                             unsigned* __restrict__ pcnt, unsigned long long* __restrict__ ppk) {
  int i = blockIdx.x * 256 + threadIdx.x;   // 0..16383
  int c = labels[i] & 15;
  float v = scores[i * NCLS + c];
  unsigned idx = atomicAdd(&pcnt[c], 1u);
  ppk[(c << 14) + idx] = ((unsigned long long)(~ordkey(v)) << 32) | (unsigned)i;
}

// ---- positives: rank (descending, stable-equivalent) + scatter sorted values ----
#define PCAP 4096
__global__ void k_posrank2(const float* __restrict__ scores,
                           const unsigned long long* __restrict__ ppk,
                           const unsigned* __restrict__ pcnt, float* __restrict__ spos) {
  int c = blockIdx.y;
  unsigned P = pcnt[c];
  int tid = threadIdx.x;
  __shared__ unsigned long long pk[PCAP];
  const unsigned long long* src = ppk + ((size_t)c << 14);
  if (P <= PCAP) {
    for (unsigned t = tid; t < P; t += 256) pk[t] = src[t];
    __syncthreads();
    for (unsigned q = blockIdx.x * 256 + tid; q < P; q += gridDim.x * 256) {
      unsigned long long k64 = pk[q];
      unsigned cq = 0;
      for (unsigned t = 0; t < P; ++t) cq += (pk[t] < k64) ? 1u : 0u;
      unsigned i = (unsigned)(k64 & 0xFFFFFFFFu);
      spos[(c << 14) + cq] = scores[i * NCLS + c];
    }
  } else { // safety fallback: global-memory version (won't trigger for this input)
    for (unsigned q = blockIdx.x * 256 + tid; q < P; q += gridDim.x * 256) {
      unsigned long long k64 = src[q];
      unsigned cq = 0;
      for (unsigned t = 0; t < P; ++t) cq += (src[t] < k64) ? 1u : 0u;
      unsigned i = (unsigned)(k64 & 0xFFFFFFFFu);
      spos[(c << 14) + cq] = scores[i * NCLS + c];
    }
  }
}

// ---- per-class exclusive prefix over 65536 buckets (1 block/class, 1024 thr) ----
__global__ void k_scan1(unsigned* __restrict__ h1) {
  int c = blockIdx.x;
  unsigned* h = h1 + ((size_t)c << 16);
  int tid = threadIdx.x;           // 0..1023, each owns 64 consecutive buckets
  unsigned base = (unsigned)tid << 6;
  unsigned s = 0;
  for (int q = 0; q < 64; ++q) s += h[base + q];
  __shared__ unsigned part[1024];
  part[tid] = s;
  __syncthreads();
  for (int off = 1; off < 1024; off <<= 1) {
    unsigned v = (tid >= off) ? part[tid - off] : 0u;
    __syncthreads();
    part[tid] += v;
    __syncthreads();
  }
  unsigned running = part[tid] - s;   // exclusive prefix of this thread's chunk
  for (int q = 0; q < 64; ++q) {
    unsigned tmp = h[base + q];
    h[base + q] = running;
    running += tmp;
  }
}

// ---- scatter negatives into bucket-grouped array; h1[b] becomes bucket END ----
__global__ void k_scatter(const float* __restrict__ col, const int* __restrict__ labels,
                          unsigned* __restrict__ h1, unsigned* __restrict__ pack) {
  int t = blockIdx.x * 256 + threadIdx.x;
  int c = t >> 14, i = t & 16383;
  if (labels[i] != c) {
    unsigned k = ordkey(col[t]);
    unsigned p = atomicAdd(&h1[(c << 16) + (k >> 16)], 1u);
    pack[(c << 14) + p] = (k << 16) | (unsigned)i;
  }
}

// ---- final rank: bucket start + count of smaller same-bucket entries ----
// Scatters the negative's score by ascending rank into sneg (downstream kernels
// need only rank-ordered scores, not item identity).
__global__ void k_rankfine(const float* __restrict__ col, const int* __restrict__ labels,
                           const unsigned* __restrict__ h1, const unsigned* __restrict__ pack,
                           float* __restrict__ sneg) {
  int t = blockIdx.x * 256 + threadIdx.x;
  int c = t >> 14, i = t & 16383;
  if (labels[i] != c) {
    float v = col[t];
    unsigned k = ordkey(v);
    unsigned b = k >> 16;
    const unsigned* hb = h1 + ((size_t)c << 16);
    unsigned start = b ? hb[b - 1] : 0u;   // after scatter: hb[x] = end of bucket x
    unsigned end = hb[b];
    unsigned mine = (k << 16) | (unsigned)i;
    const unsigned* pk = pack + (c << 14);
    unsigned cnt = start;
    for (unsigned q = start; q < end; ++q) cnt += (pk[q] < mine) ? 1u : 0u;
    sneg[(c << 14) + cnt] = v;             // cnt = 0-based ascending rank (unique)
  }
}

// ============================================================================
// opt_j is monotone NON-INCREASING in ascending rank j (the property the
// reference's original quickselect D&C exploits; asserted in its docstring).
// Anchors every ASTEP ranks bracket every intermediate opt. Anchors use the
// EXACT sequential backward scan (identical float op order to the validated
// full kernel); the fill pass scans only [opt_hi-2, opt_lo+2] of a truncated
// suffix, which is argmax-equivalent (constant shift) and keeps the
// first-max-on-tie rule.
// ============================================================================
#define SCAP 2048
#define HCAP 2048
#define ABITS 6
#define ASTEP 64

__global__ void k_anchor(const unsigned* __restrict__ counts, const float* __restrict__ spos,
                         const float* __restrict__ sneg, unsigned* __restrict__ aopt) {
  int c = blockIdx.y;
  int P = (int)counts[c];
  int N = C_ITEMS - P;
  if (P == 0 || N == 0) return;
  int tid = threadIdx.x;
  __shared__ float sp[SCAP];
  int stageN = (P <= SCAP) ? P : 0;
  for (int t = tid; t < stageN; t += 256) sp[t] = spos[(c << 14) + t];
  __syncthreads();
  int T = (N + ASTEP - 1) / ASTEP + 1;      // full anchors + terminal anchor at N-1
  float invP = 1.0f / (float)P;
  float coef = 2.0f / ((float)P * (float)N);
  for (int t = tid; t < T; t += 256) {
    int j0 = min(t * ASTEP, N - 1);
    float v = sneg[(c << 14) + j0];
    float a = coef * v;
    float fcnt = (float)(j0 + P + 1);
    float s = 0.0f, best = 0.0f;
    int besti = P;
    if (P <= SCAP) {
      for (int q = P - 1; q >= 0; --q) {
        float spv = sp[q];
        float r = __builtin_amdgcn_rcpf(fcnt);
        float delta = fmaf(invP, r, fmaf(-coef, spv, a));
        s += delta;
        if (s >= best) { best = s; besti = q; }
        fcnt -= 1.0f;
      }
    } else {
      const float* spg = spos + ((size_t)c << 14);
      for (int q = P - 1; q >= 0; --q) {
        float spv = spg[q];
        float r = __builtin_amdgcn_rcpf(fcnt);
        float delta = fmaf(invP, r, fmaf(-coef, spv, a));
        s += delta;
        if (s >= best) { best = s; besti = q; }
        fcnt -= 1.0f;
      }
    }
    aopt[(c << 9) + t] = (unsigned)(besti + 1);
  }
}

// ---- bracketed per-negative argmax + histogram + minus-side sums ----
__global__ void k_optB(const unsigned* __restrict__ counts, const float* __restrict__ spos,
                       const float* __restrict__ sneg, const unsigned* __restrict__ aopt,
                       unsigned* __restrict__ hist, double* __restrict__ accS,
                       double* __restrict__ accV) {
  int c = blockIdx.y;
  int P = (int)counts[c];
  int N = C_ITEMS - P;
  if (P == 0 || N == 0) return;
  int tid = threadIdx.x;
  int j0 = blockIdx.x * 256 + tid;
  bool active = (j0 < N);
  __shared__ float sp[SCAP];
  __shared__ unsigned lh[HCAP];
  __shared__ double red[256];
  int stageN = (P <= SCAP) ? P : 0;
  for (int t = tid; t < stageN; t += 256) sp[t] = spos[(c << 14) + t];
  for (int t = tid; t < HCAP; t += 256) lh[t] = 0u;
  __syncthreads();
  int opt = P + 1;
  float v = 0.0f;
  if (active) {
    v = sneg[(c << 14) + j0];
    int g = j0 >> ABITS;
    int hiA = (int)aopt[(c << 9) + g];
    if ((j0 & (ASTEP - 1)) == 0) {
      opt = hiA;                      // anchor rank: exact full-scan value
    } else {
      int loA = (int)aopt[(c << 9) + g + 1];
      int hi = min(hiA + 2, P + 1);   // +-2 margin absorbs float near-tie wobble
      int lo = max(loA - 2, 1);
      float invP = 1.0f / (float)P;
      float coef = 2.0f / ((float)P * (float)N);
      float a = coef * v;
      float s = 0.0f, best = 0.0f;
      int bestr = hi;                 // empty suffix (value 0) candidate at r=hi
      float fcnt = (float)(j0 + hi);  // j0+1+k at k=hi-1
      if (P <= SCAP) {
        for (int k = hi - 1; k >= lo; --k) {
          float spv = sp[k - 1];
          float r = __builtin_amdgcn_rcpf(fcnt);
          float delta = fmaf(invP, r, fmaf(-coef, spv, a));
          s += delta;
          if (s >= best) { best = s; bestr = k; }
          fcnt -= 1.0f;
        }
      } else {
        const float* spg = spos + ((size_t)c << 14);
        for (int k = hi - 1; k >= lo; --k) {
          float spv = spg[k - 1];
          float r = __builtin_amdgcn_rcpf(fcnt);
          float delta = fmaf(invP, r, fmaf(-coef, spv, a));
          s += delta;
          if (s >= best) { best = s; bestr = k; }
          fcnt -= 1.0f;
        }
      }
      opt = bestr;
    }
  }
  if (P + 2 <= HCAP) {
    if (active) atomicAdd(&lh[opt], 1u);
    __syncthreads();
    for (int t = tid; t < P + 2; t += 256)
      if (lh[t]) atomicAdd(&hist[c * HSTRIDE + t], lh[t]);
  } else {
    if (active) atomicAdd(&hist[c * HSTRIDE + opt], 1u);
  }
  double cm = active ? (double)(P + 2 - 2 * opt) * (double)v : 0.0;
  double sv = active ? (double)v : 0.0;
  red[tid] = cm; __syncthreads();
  for (int sh = 128; sh > 0; sh >>= 1) { if (tid < sh) red[tid] += red[tid + sh]; __syncthreads(); }
  if (tid == 0) atomicAdd(&accS[c], red[0]);
  __syncthreads();
  red[tid] = sv; __syncthreads();
  for (int sh = 128; sh > 0; sh >>= 1) { if (tid < sh) red[tid] += red[tid + sh]; __syncthreads(); }
  if (tid == 0) atomicAdd(&accV[c], red[0]);
}

// ---- per-class: prefix-sum hist -> r_plus, plus-side sums, loss ----
__global__ void k_finalize(const unsigned* __restrict__ counts, const unsigned* __restrict__ hist,
                           const float* __restrict__ spos, const double* __restrict__ accS,
                           const double* __restrict__ accV, double* __restrict__ total) {
  int c = blockIdx.x;
  int tid = threadIdx.x;
  int P = (int)counts[c];
  int N = C_ITEMS - P;
  if (P == 0 || N == 0) return;
  __shared__ unsigned sc[256];
  __shared__ double red[256];
  const unsigned* h = hist + c * HSTRIDE;
  int M = P + 1;
  int L = (M + 255) / 256;
  int o0 = 1 + tid * L;
  int o1 = min(o0 + L, P + 2);
  unsigned part = 0;
  for (int o = o0; o < o1; ++o) part += h[o];
  sc[tid] = part;
  __syncthreads();
  if (tid == 0) {
    unsigned runp = 0;
    for (int t = 0; t < 256; ++t) { unsigned tmp = sc[t]; sc[t] = runp; runp += tmp; }
  }
  __syncthreads();
  unsigned run = sc[tid];
  double a1 = 0.0, a2 = 0.0, a3 = 0.0;
  for (int o = o0; o < o1; ++o) {
    run += h[o];
    if (o <= P) {
      int k0 = o - 1;
      double rp = 1.0 + (double)run;
      double spv = (double)spos[(c << 14) + k0];
      a1 += (double)(k0 + 1) / ((double)k0 + rp);
      a2 += spv * ((double)N + 2.0 - 2.0 * rp);
      a3 += spv;
    }
  }
  red[tid] = a1; __syncthreads();
  for (int s = 128; s > 0; s >>= 1) { if (tid < s) red[tid] += red[tid + s]; __syncthreads(); }
  double r1 = red[0]; __syncthreads();
  red[tid] = a2; __syncthreads();
  for (int s = 128; s > 0; s >>= 1) { if (tid < s) red[tid] += red[tid + s]; __syncthreads(); }
  double r2 = red[0]; __syncthreads();
  red[tid] = a3; __syncthreads();
  for (int s = 128; s > 0; s >>= 1) { if (tid < s) red[tid] += red[tid + s]; __syncthreads(); }
  double r3 = red[0];
  if (tid == 0) {
    double Pd = (double)P, Nd = (double)N;
    double FR  = r2 + accS[c];
    double FRs = Nd * r3 - Pd * accV[c];
    double lc  = (1.0 - r1 / Pd) + (FR - FRs) / (Pd * Nd);
    atomicAdd(total, lc);
  }
}

__global__ void k_out(const double* __restrict__ total, float* __restrict__ out) {
  out[0] = (float)(total[0] / (double)NCLS);
}

extern "C" void kernel_launch(void* const* d_in, const int* in_sizes, int n_in,
                              void* d_out, int out_size, void* d_ws, size_t ws_size,
                              hipStream_t stream) {
  (void)in_sizes; (void)n_in; (void)out_size; (void)ws_size;
  const float* scores = (const float*)d_in[0];
  const int* labels = (const int*)d_in[1];
  float* out = (float*)d_out;
  char* ws = (char*)d_ws;
  float* col      = (float*)(ws + OFF_COL);
  float* spos     = (float*)(ws + OFF_SPOS);
  float* sneg     = (float*)(ws + OFF_SNEG);
  unsigned* pack  = (unsigned*)(ws + OFF_PACK);
  unsigned* hist  = (unsigned*)(ws + OFF_HIST);
  unsigned* counts= (unsigned*)(ws + OFF_CNT);
  double* accS    = (double*)(ws + OFF_ACCS);
  double* accV    = (double*)(ws + OFF_ACCV);
  double* total   = (double*)(ws + OFF_TOT);
  unsigned* pcnt  = (unsigned*)(ws + OFF_PC);
  unsigned* h1    = (unsigned*)(ws + OFF_H1);
  unsigned long long* ppk = (unsigned long long*)(ws + OFF_PPK);
  unsigned* aopt  = (unsigned*)(ws + OFF_PPK);  // reused after k_posrank2

  int zn = (int)(ZERO_BYTES / 4);
  k_zero<<<1024, 256, 0, stream>>>(hist, zn);               // zeroes hist..h1 (contiguous)
  k_prep<<<1024, 256, 0, stream>>>(scores, labels, col, h1);
  k_counts<<<64, 256, 0, stream>>>(labels, counts);
  k_poscollect<<<64, 256, 0, stream>>>(scores, labels, pcnt, ppk);
  k_posrank2<<<dim3(16, NCLS), 256, 0, stream>>>(scores, ppk, pcnt, spos);
  k_scan1<<<NCLS, 1024, 0, stream>>>(h1);
  k_scatter<<<1024, 256, 0, stream>>>(col, labels, h1, pack);
  k_rankfine<<<1024, 256, 0, stream>>>(col, labels, h1, pack, sneg);
  k_anchor<<<dim3(1, NCLS), 256, 0, stream>>>(counts, spos, sneg, aopt);
  k_optB<<<dim3(64, NCLS), 256, 0, stream>>>(counts, spos, sneg, aopt, hist, accS, accV);
  k_finalize<<<NCLS, 256, 0, stream>>>(counts, hist, spos, accS, accV, total);
  k_out<<<1, 1, 0, stream>>>(total, out);
}

// Round 3
// 215.869 us; speedup vs baseline: 1.3863x; 1.1962x over previous
//
#include <hip/hip_runtime.h>
#include <stdint.h>

#define C_ITEMS 16384
#define NCLS 16
#define HSTRIDE 16386   // AP hist entries per class (opt in [1, P+1])

// ---- workspace layout (bytes) ----
static const size_t OFF_COL  = 0;                                     // 16*16384 f32 col-major scores
static const size_t OFF_SPOS = 1u << 20;                              // sorted positives (desc) per class
static const size_t OFF_SNEG = 2u << 20;                              // per-(class,rank) negative score (f32)
static const size_t OFF_PACK = 3u << 20;                              // bucket-scattered (low16key,idx)
static const size_t OFF_HIST = 4u << 20;                              // 16 * HSTRIDE u32 (AP hist)
static const size_t OFF_CNT  = OFF_HIST + (size_t)NCLS * HSTRIDE * 4; // 16 u32 (unused; kept for layout)
static const size_t OFF_ACCS = OFF_CNT + 64;                          // 16 double
static const size_t OFF_ACCV = OFF_ACCS + 128;                        // 16 double
static const size_t OFF_TOT  = OFF_ACCV + 128;                        // 1 double
static const size_t OFF_PC   = OFF_TOT + 8;                           // 16 u32 positive counters (= per-class P)
static const size_t OFF_H1   = (OFF_PC + 64 + 255) & ~(size_t)255;    // 16 * 65536 u32 bucket hist
static const size_t OFF_PPK  = OFF_H1 + (((size_t)NCLS << 16) * 4);   // 16 * 16384 u64 positive keys
static const size_t ZERO_BYTES = OFF_PPK - OFF_HIST;                  // zero hist..h1 end
// aopt (anchor opts, 16 * 512 u32) reuses the ppk region: written by k_anchor
// strictly after k_posrank2 consumed ppk. No extra workspace, no zeroing needed.

__device__ __forceinline__ unsigned ordkey(float f) {
  unsigned b = __float_as_uint(f);
  return (b & 0x80000000u) ? ~b : (b | 0x80000000u);   // monotone float->uint
}

__global__ void k_zero(unsigned* p, int n) {
  int stride = gridDim.x * blockDim.x;
  for (int t = blockIdx.x * blockDim.x + threadIdx.x; t < n; t += stride) p[t] = 0u;
}

// transpose + per-class negative bucket histogram (65536 buckets on ordkey>>16)
__global__ void k_prep(const float* __restrict__ scores, const int* __restrict__ labels,
                       float* __restrict__ col, unsigned* __restrict__ h1) {
  int t = blockIdx.x * 256 + threadIdx.x;      // 0..262143
  float v = scores[t];
  int i = t >> 4, c = t & 15;
  col[(c << 14) | i] = v;
  if (labels[i] != c)
    atomicAdd(&h1[(c << 16) + (ordkey(v) >> 16)], 1u);
}

// ---- positives: collect (key,idx) per class into global lists ----
// Two-level reservation: LDS per-block histogram -> one global atomic per
// (block,class) -> direct write. Replaces 16384 same-address global atomics
// (~43 us of pure L2-atomic serialization) with <=1024 spread ones.
// pcnt ends holding the per-class positive count P (used downstream as counts).
__global__ void k_poscollect(const float* __restrict__ scores, const int* __restrict__ labels,
                             unsigned* __restrict__ pcnt, unsigned long long* __restrict__ ppk) {
  __shared__ unsigned lc[NCLS];
  __shared__ unsigned base[NCLS];
  int tid = threadIdx.x;
  if (tid < NCLS) lc[tid] = 0;
  __syncthreads();
  int i = blockIdx.x * 256 + tid;   // 0..16383
  int c = labels[i] & 15;
  float v = scores[i * NCLS + c];
  unsigned loc = atomicAdd(&lc[c], 1u);
  __syncthreads();
  if (tid < NCLS) base[tid] = lc[tid] ? atomicAdd(&pcnt[tid], lc[tid]) : 0u;
  __syncthreads();
  ppk[(c << 14) + base[c] + loc] = ((unsigned long long)(~ordkey(v)) << 32) | (unsigned)i;
}

// ---- positives: rank (descending, stable-equivalent) + scatter sorted values ----
// Keys are unique (idx in low bits), so rank-by-counting is permutation-invariant
// w.r.t. ppk list order.
#define PCAP 4096
__global__ void k_posrank2(const float* __restrict__ scores,
                           const unsigned long long* __restrict__ ppk,
                           const unsigned* __restrict__ pcnt, float* __restrict__ spos) {
  int c = blockIdx.y;
  unsigned P = pcnt[c];
  int tid = threadIdx.x;
  __shared__ unsigned long long pk[PCAP];
  const unsigned long long* src = ppk + ((size_t)c << 14);
  if (P <= PCAP) {
    for (unsigned t = tid; t < P; t += 256) pk[t] = src[t];
    __syncthreads();
    for (unsigned q = blockIdx.x * 256 + tid; q < P; q += gridDim.x * 256) {
      unsigned long long k64 = pk[q];
      unsigned cq = 0;
      for (unsigned t = 0; t < P; ++t) cq += (pk[t] < k64) ? 1u : 0u;
      unsigned i = (unsigned)(k64 & 0xFFFFFFFFu);
      spos[(c << 14) + cq] = scores[i * NCLS + c];
    }
  } else { // safety fallback: global-memory version (won't trigger for this input)
    for (unsigned q = blockIdx.x * 256 + tid; q < P; q += gridDim.x * 256) {
      unsigned long long k64 = src[q];
      unsigned cq = 0;
      for (unsigned t = 0; t < P; ++t) cq += (src[t] < k64) ? 1u : 0u;
      unsigned i = (unsigned)(k64 & 0xFFFFFFFFu);
      spos[(c << 14) + cq] = scores[i * NCLS + c];
    }
  }
}

// ---- per-class exclusive prefix over 65536 buckets (1 block/class, 1024 thr) ----
__global__ void k_scan1(unsigned* __restrict__ h1) {
  int c = blockIdx.x;
  unsigned* h = h1 + ((size_t)c << 16);
  int tid = threadIdx.x;           // 0..1023, each owns 64 consecutive buckets
  unsigned base = (unsigned)tid << 6;
  unsigned s = 0;
  for (int q = 0; q < 64; ++q) s += h[base + q];
  __shared__ unsigned part[1024];
  part[tid] = s;
  __syncthreads();
  for (int off = 1; off < 1024; off <<= 1) {
    unsigned v = (tid >= off) ? part[tid - off] : 0u;
    __syncthreads();
    part[tid] += v;
    __syncthreads();
  }
  unsigned running = part[tid] - s;   // exclusive prefix of this thread's chunk
  for (int q = 0; q < 64; ++q) {
    unsigned tmp = h[base + q];
    h[base + q] = running;
    running += tmp;
  }
}

// ---- scatter negatives into bucket-grouped array; h1[b] becomes bucket END ----
__global__ void k_scatter(const float* __restrict__ col, const int* __restrict__ labels,
                          unsigned* __restrict__ h1, unsigned* __restrict__ pack) {
  int t = blockIdx.x * 256 + threadIdx.x;
  int c = t >> 14, i = t & 16383;
  if (labels[i] != c) {
    unsigned k = ordkey(col[t]);
    unsigned p = atomicAdd(&h1[(c << 16) + (k >> 16)], 1u);
    pack[(c << 14) + p] = (k << 16) | (unsigned)i;
  }
}

// ---- final rank: bucket start + count of smaller same-bucket entries ----
// Scatters the negative's score by ascending rank into sneg (downstream kernels
// need only rank-ordered scores, not item identity).
__global__ void k_rankfine(const float* __restrict__ col, const int* __restrict__ labels,
                           const unsigned* __restrict__ h1, const unsigned* __restrict__ pack,
                           float* __restrict__ sneg) {
  int t = blockIdx.x * 256 + threadIdx.x;
  int c = t >> 14, i = t & 16383;
  if (labels[i] != c) {
    float v = col[t];
    unsigned k = ordkey(v);
    unsigned b = k >> 16;
    const unsigned* hb = h1 + ((size_t)c << 16);
    unsigned start = b ? hb[b - 1] : 0u;   // after scatter: hb[x] = end of bucket x
    unsigned end = hb[b];
    unsigned mine = (k << 16) | (unsigned)i;
    const unsigned* pk = pack + (c << 14);
    unsigned cnt = start;
    for (unsigned q = start; q < end; ++q) cnt += (pk[q] < mine) ? 1u : 0u;
    sneg[(c << 14) + cnt] = v;             // cnt = 0-based ascending rank (unique)
  }
}

// ============================================================================
// opt_j is monotone NON-INCREASING in ascending rank j (the property the
// reference's original quickselect D&C exploits; asserted in its docstring).
// Anchors every ASTEP ranks bracket every intermediate opt. Anchors use the
// EXACT sequential backward scan (identical float op order to the validated
// full kernel); the fill pass scans only [opt_hi-2, opt_lo+2] of a truncated
// suffix, which is argmax-equivalent (constant shift) and keeps the
// first-max-on-tie rule.
// ============================================================================
#define SCAP 2048
#define HCAP 2048
#define ABITS 6
#define ASTEP 64

__global__ void k_anchor(const unsigned* __restrict__ counts, const float* __restrict__ spos,
                         const float* __restrict__ sneg, unsigned* __restrict__ aopt) {
  int c = blockIdx.y;
  int P = (int)counts[c];
  int N = C_ITEMS - P;
  if (P == 0 || N == 0) return;
  int tid = threadIdx.x;
  __shared__ float sp[SCAP];
  int stageN = (P <= SCAP) ? P : 0;
  for (int t = tid; t < stageN; t += 256) sp[t] = spos[(c << 14) + t];
  __syncthreads();
  int T = (N + ASTEP - 1) / ASTEP + 1;      // full anchors + terminal anchor at N-1
  float invP = 1.0f / (float)P;
  float coef = 2.0f / ((float)P * (float)N);
  for (int t = tid; t < T; t += 256) {
    int j0 = min(t * ASTEP, N - 1);
    float v = sneg[(c << 14) + j0];
    float a = coef * v;
    float fcnt = (float)(j0 + P + 1);
    float s = 0.0f, best = 0.0f;
    int besti = P;
    if (P <= SCAP) {
      for (int q = P - 1; q >= 0; --q) {
        float spv = sp[q];
        float r = __builtin_amdgcn_rcpf(fcnt);
        float delta = fmaf(invP, r, fmaf(-coef, spv, a));
        s += delta;
        if (s >= best) { best = s; besti = q; }
        fcnt -= 1.0f;
      }
    } else {
      const float* spg = spos + ((size_t)c << 14);
      for (int q = P - 1; q >= 0; --q) {
        float spv = spg[q];
        float r = __builtin_amdgcn_rcpf(fcnt);
        float delta = fmaf(invP, r, fmaf(-coef, spv, a));
        s += delta;
        if (s >= best) { best = s; besti = q; }
        fcnt -= 1.0f;
      }
    }
    aopt[(c << 9) + t] = (unsigned)(besti + 1);
  }
}

// ---- bracketed per-negative argmax + histogram + minus-side sums ----
__global__ void k_optB(const unsigned* __restrict__ counts, const float* __restrict__ spos,
                       const float* __restrict__ sneg, const unsigned* __restrict__ aopt,
                       unsigned* __restrict__ hist, double* __restrict__ accS,
                       double* __restrict__ accV) {
  int c = blockIdx.y;
  int P = (int)counts[c];
  int N = C_ITEMS - P;
  if (P == 0 || N == 0) return;
  int tid = threadIdx.x;
  int j0 = blockIdx.x * 256 + tid;
  bool active = (j0 < N);
  __shared__ float sp[SCAP];
  __shared__ unsigned lh[HCAP];
  __shared__ double red[256];
  int stageN = (P <= SCAP) ? P : 0;
  for (int t = tid; t < stageN; t += 256) sp[t] = spos[(c << 14) + t];
  for (int t = tid; t < HCAP; t += 256) lh[t] = 0u;
  __syncthreads();
  int opt = P + 1;
  float v = 0.0f;
  if (active) {
    v = sneg[(c << 14) + j0];
    int g = j0 >> ABITS;
    int hiA = (int)aopt[(c << 9) + g];
    if ((j0 & (ASTEP - 1)) == 0) {
      opt = hiA;                      // anchor rank: exact full-scan value
    } else {
      int loA = (int)aopt[(c << 9) + g + 1];
      int hi = min(hiA + 2, P + 1);   // +-2 margin absorbs float near-tie wobble
      int lo = max(loA - 2, 1);
      float invP = 1.0f / (float)P;
      float coef = 2.0f / ((float)P * (float)N);
      float a = coef * v;
      float s = 0.0f, best = 0.0f;
      int bestr = hi;                 // empty suffix (value 0) candidate at r=hi
      float fcnt = (float)(j0 + hi);  // j0+1+k at k=hi-1
      if (P <= SCAP) {
        for (int k = hi - 1; k >= lo; --k) {
          float spv = sp[k - 1];
          float r = __builtin_amdgcn_rcpf(fcnt);
          float delta = fmaf(invP, r, fmaf(-coef, spv, a));
          s += delta;
          if (s >= best) { best = s; bestr = k; }
          fcnt -= 1.0f;
        }
      } else {
        const float* spg = spos + ((size_t)c << 14);
        for (int k = hi - 1; k >= lo; --k) {
          float spv = spg[k - 1];
          float r = __builtin_amdgcn_rcpf(fcnt);
          float delta = fmaf(invP, r, fmaf(-coef, spv, a));
          s += delta;
          if (s >= best) { best = s; bestr = k; }
          fcnt -= 1.0f;
        }
      }
      opt = bestr;
    }
  }
  if (P + 2 <= HCAP) {
    if (active) atomicAdd(&lh[opt], 1u);
    __syncthreads();
    for (int t = tid; t < P + 2; t += 256)
      if (lh[t]) atomicAdd(&hist[c * HSTRIDE + t], lh[t]);
  } else {
    if (active) atomicAdd(&hist[c * HSTRIDE + opt], 1u);
  }
  double cm = active ? (double)(P + 2 - 2 * opt) * (double)v : 0.0;
  double sv = active ? (double)v : 0.0;
  red[tid] = cm; __syncthreads();
  for (int sh = 128; sh > 0; sh >>= 1) { if (tid < sh) red[tid] += red[tid + sh]; __syncthreads(); }
  if (tid == 0) atomicAdd(&accS[c], red[0]);
  __syncthreads();
  red[tid] = sv; __syncthreads();
  for (int sh = 128; sh > 0; sh >>= 1) { if (tid < sh) red[tid] += red[tid + sh]; __syncthreads(); }
  if (tid == 0) atomicAdd(&accV[c], red[0]);
}

// ---- per-class: prefix-sum hist -> r_plus, plus-side sums, loss ----
__global__ void k_finalize(const unsigned* __restrict__ counts, const unsigned* __restrict__ hist,
                           const float* __restrict__ spos, const double* __restrict__ accS,
                           const double* __restrict__ accV, double* __restrict__ total) {
  int c = blockIdx.x;
  int tid = threadIdx.x;
  int P = (int)counts[c];
  int N = C_ITEMS - P;
  if (P == 0 || N == 0) return;
  __shared__ unsigned sc[256];
  __shared__ double red[256];
  const unsigned* h = hist + c * HSTRIDE;
  int M = P + 1;
  int L = (M + 255) / 256;
  int o0 = 1 + tid * L;
  int o1 = min(o0 + L, P + 2);
  unsigned part = 0;
  for (int o = o0; o < o1; ++o) part += h[o];
  sc[tid] = part;
  __syncthreads();
  if (tid == 0) {
    unsigned runp = 0;
    for (int t = 0; t < 256; ++t) { unsigned tmp = sc[t]; sc[t] = runp; runp += tmp; }
  }
  __syncthreads();
  unsigned run = sc[tid];
  double a1 = 0.0, a2 = 0.0, a3 = 0.0;
  for (int o = o0; o < o1; ++o) {
    run += h[o];
    if (o <= P) {
      int k0 = o - 1;
      double rp = 1.0 + (double)run;
      double spv = (double)spos[(c << 14) + k0];
      a1 += (double)(k0 + 1) / ((double)k0 + rp);
      a2 += spv * ((double)N + 2.0 - 2.0 * rp);
      a3 += spv;
    }
  }
  red[tid] = a1; __syncthreads();
  for (int s = 128; s > 0; s >>= 1) { if (tid < s) red[tid] += red[tid + s]; __syncthreads(); }
  double r1 = red[0]; __syncthreads();
  red[tid] = a2; __syncthreads();
  for (int s = 128; s > 0; s >>= 1) { if (tid < s) red[tid] += red[tid + s]; __syncthreads(); }
  double r2 = red[0]; __syncthreads();
  red[tid] = a3; __syncthreads();
  for (int s = 128; s > 0; s >>= 1) { if (tid < s) red[tid] += red[tid + s]; __syncthreads(); }
  double r3 = red[0];
  if (tid == 0) {
    double Pd = (double)P, Nd = (double)N;
    double FR  = r2 + accS[c];
    double FRs = Nd * r3 - Pd * accV[c];
    double lc  = (1.0 - r1 / Pd) + (FR - FRs) / (Pd * Nd);
    atomicAdd(total, lc);
  }
}

__global__ void k_out(const double* __restrict__ total, float* __restrict__ out) {
  out[0] = (float)(total[0] / (double)NCLS);
}

extern "C" void kernel_launch(void* const* d_in, const int* in_sizes, int n_in,
                              void* d_out, int out_size, void* d_ws, size_t ws_size,
                              hipStream_t stream) {
  (void)in_sizes; (void)n_in; (void)out_size; (void)ws_size;
  const float* scores = (const float*)d_in[0];
  const int* labels = (const int*)d_in[1];
  float* out = (float*)d_out;
  char* ws = (char*)d_ws;
  float* col      = (float*)(ws + OFF_COL);
  float* spos     = (float*)(ws + OFF_SPOS);
  float* sneg     = (float*)(ws + OFF_SNEG);
  unsigned* pack  = (unsigned*)(ws + OFF_PACK);
  unsigned* hist  = (unsigned*)(ws + OFF_HIST);
  double* accS    = (double*)(ws + OFF_ACCS);
  double* accV    = (double*)(ws + OFF_ACCV);
  double* total   = (double*)(ws + OFF_TOT);
  unsigned* pcnt  = (unsigned*)(ws + OFF_PC);   // doubles as per-class P counts
  unsigned* h1    = (unsigned*)(ws + OFF_H1);
  unsigned long long* ppk = (unsigned long long*)(ws + OFF_PPK);
  unsigned* aopt  = (unsigned*)(ws + OFF_PPK);  // reused after k_posrank2

  int zn = (int)(ZERO_BYTES / 4);
  k_zero<<<1024, 256, 0, stream>>>(hist, zn);               // zeroes hist..h1 (contiguous)
  k_prep<<<1024, 256, 0, stream>>>(scores, labels, col, h1);
  k_poscollect<<<64, 256, 0, stream>>>(scores, labels, pcnt, ppk);
  k_posrank2<<<dim3(16, NCLS), 256, 0, stream>>>(scores, ppk, pcnt, spos);
  k_scan1<<<NCLS, 1024, 0, stream>>>(h1);
  k_scatter<<<1024, 256, 0, stream>>>(col, labels, h1, pack);
  k_rankfine<<<1024, 256, 0, stream>>>(col, labels, h1, pack, sneg);
  k_anchor<<<dim3(1, NCLS), 256, 0, stream>>>(pcnt, spos, sneg, aopt);
  k_optB<<<dim3(64, NCLS), 256, 0, stream>>>(pcnt, spos, sneg, aopt, hist, accS, accV);
  k_finalize<<<NCLS, 256, 0, stream>>>(pcnt, hist, spos, accS, accV, total);
  k_out<<<1, 1, 0, stream>>>(total, out);
}